// Round 4
// baseline (528.921 us; speedup 1.0000x reference)
//
#include <hip/hip_runtime.h>
#include <cstddef>

namespace {
constexpr int S = 512;
constexpr int B = 64;
constexpr int H = 768;
constexpr int T = 32;
constexpr int START = 30;
constexpr int END = 31;
}

// ---------------------------------------------------------------------------
// Kernel 1: emissions. emitT[b][s][t] = dot(emb[s,b,:], W[:,t]) + bias[t]
// ---------------------------------------------------------------------------
__global__ __launch_bounds__(256) void emit_gemm(const float* __restrict__ A,
                                                 const float* __restrict__ W,
                                                 const float* __restrict__ bias,
                                                 float* __restrict__ emitT) {
  __shared__ __align__(16) float At[64][64];
  __shared__ __align__(16) float Wl[64][32];
  const int tid = threadIdx.x;
  const int s = blockIdx.x;
  const int t = tid & 31;
  const int r0 = tid >> 5;
  float acc[8];
#pragma unroll
  for (int k = 0; k < 8; ++k) acc[k] = 0.f;
  const float* Ablk = A + (size_t)s * B * H;
  const int rr = tid >> 4;
  const int hh = (tid & 15) << 2;

  for (int hc = 0; hc < H; hc += 64) {
    {
      const float4* Wg = (const float4*)(W + hc * T);
      float4* Wd = (float4*)(&Wl[0][0]);
      Wd[tid] = Wg[tid];
      Wd[tid + 256] = Wg[tid + 256];
    }
#pragma unroll
    for (int i = 0; i < 4; ++i) {
      const int r = rr + 16 * i;
      float4 v = *(const float4*)(Ablk + (size_t)r * H + hc + hh);
      At[hh + 0][r] = v.x;
      At[hh + 1][r] = v.y;
      At[hh + 2][r] = v.z;
      At[hh + 3][r] = v.w;
    }
    __syncthreads();
#pragma unroll 8
    for (int h = 0; h < 64; ++h) {
      const float w = Wl[h][t];
      const float4* ap = (const float4*)(&At[h][r0 * 8]);
      float4 a0 = ap[0];
      float4 a1 = ap[1];
      acc[0] = fmaf(a0.x, w, acc[0]);
      acc[1] = fmaf(a0.y, w, acc[1]);
      acc[2] = fmaf(a0.z, w, acc[2]);
      acc[3] = fmaf(a0.w, w, acc[3]);
      acc[4] = fmaf(a1.x, w, acc[4]);
      acc[5] = fmaf(a1.y, w, acc[5]);
      acc[6] = fmaf(a1.z, w, acc[6]);
      acc[7] = fmaf(a1.w, w, acc[7]);
    }
    __syncthreads();
  }
  const float bb = bias[t];
#pragma unroll
  for (int k = 0; k < 8; ++k) {
    const int b = r0 * 8 + k;
    emitT[((size_t)b * S + s) * T + t] = acc[k] + bb;
  }
}

// ---------------------------------------------------------------------------
// Kernel 2: CRF scan. 128 blocks x 64 threads (one wave each).
// blocks 0..63: alpha (scaled-prob domain) + gold -> nll.
// blocks 64..127: viterbi (log domain) + pointer-doubling backtrace.
// dp in registers: lane l holds dp[l&31] (both halves). Per-step gather =
// 16 pipelined ds_bpermute with precomputed addresses. Cross-half combine =
// __shfl_xor(.,32) (round-2-proven; the permlane32_swap inline-asm trick was
// miscompiled via register coalescing of identical operands -- removed).
// ---------------------------------------------------------------------------
__global__ __launch_bounds__(64) void crf_scan(const float* __restrict__ emitT,
                                               const int* __restrict__ labels,
                                               const float* __restrict__ trans,
                                               float* __restrict__ out) {
  __shared__ unsigned char bp[S * T];   // backpointers (viterbi)
  __shared__ unsigned char jA[S * T];   // jump table B2 then B8
  __shared__ unsigned char jB[S * T];   // jump table B4
  __shared__ unsigned char pathb[S];
  __shared__ int anch[64];

  const int lane = threadIdx.x;
  const int b = blockIdx.x & 63;
  const bool is_vit = blockIdx.x >= 64;
  const int cur = lane & 31;
  const int h = lane >> 5;
  const int gbase = h * 16;  // this lane's 16 prev tags = gbase..gbase+15

  float tr[16];
#pragma unroll
  for (int j = 0; j < 4; ++j) {
    float4 v = *(const float4*)(trans + cur * T + gbase + 4 * j);
    tr[4 * j + 0] = v.x; tr[4 * j + 1] = v.y;
    tr[4 * j + 2] = v.z; tr[4 * j + 3] = v.w;
  }
  int adr[16];  // byte addresses for ds_bpermute: lane (gbase+i), once
#pragma unroll
  for (int i = 0; i < 16; ++i) adr[i] = (gbase + i) << 2;

  const float* ebase = emitT + (size_t)b * (S * T);
  const float* eb = ebase + cur;
  const float trS = trans[cur * T + START];
  const float e0 = eb[0];

  if (!is_vit) {
    // ================= alpha: scaled-probability domain =================
    // Invariant: dp_t[cur] = L + log(p).  Step: raw = sum_i etr[i]*p[prev_i];
    // p' = raw * exp(e)/sigma; L += log(sigma); sigma = lagged rf(raw).
    float etr[16];
#pragma unroll
    for (int i = 0; i < 16; ++i) etr[i] = __expf(tr[i]);

    float p = __expf(trS + e0);  // exact: step-0 lse collapses to trS+e0
    float L = 0.f;
    float sprev =
        __int_as_float(__builtin_amdgcn_readfirstlane(__float_as_int(p)));

    float q1 = eb[2 * T], q2 = eb[3 * T], q3 = eb[4 * T];
    float exCur = __expf(eb[1 * T]);

#pragma unroll 4
    for (int s = 1; s < S; ++s) {
      float dpv[16];
#pragma unroll
      for (int i = 0; i < 16; ++i)
        dpv[i] = __int_as_float(
            __builtin_amdgcn_ds_bpermute(adr[i], __float_as_int(p)));
      const float mult = exCur / sprev;  // off critical path (sprev lagged)
      L += __logf(sprev);                // off critical path
      float pr[16];
#pragma unroll
      for (int i = 0; i < 16; ++i) pr[i] = etr[i] * dpv[i];
#pragma unroll
      for (int i = 0; i < 8; ++i) pr[i] = pr[2 * i] + pr[2 * i + 1];
#pragma unroll
      for (int i = 0; i < 4; ++i) pr[i] = pr[2 * i] + pr[2 * i + 1];
      pr[0] = (pr[0] + pr[1]) + (pr[2] + pr[3]);
      const float raw = pr[0] + __shfl_xor(pr[0], 32);
      p = raw * mult;
      sprev =
          __int_as_float(__builtin_amdgcn_readfirstlane(__float_as_int(raw)));
      const float nq = eb[((s + 4) & (S - 1)) * T];
      const float exN = __expf(q1);
      q1 = q2; q2 = q3; q3 = nq;
      exCur = exN;
    }

    // gold path score (off the latency chain; L2-hot by now)
    float g = 0.f;
    for (int s = lane; s < S; s += 64) {
      const int c = labels[s * B + b];
      const int pl = (s == 0) ? START : labels[(s - 1) * B + b];
      g += trans[c * T + pl] + ebase[s * T + c];
    }
    if (lane == 63) g += trans[END * T + labels[(S - 1) * B + b]];

    // epilogue: logsumexp over tags of dp_final + trans[end]
    const float dpf = L + __logf(p);  // -inf for START tag (p==0): harmless
    const float v = (lane < T) ? dpf + trans[END * T + lane] : -3.0e38f;
    float mx = v;
#pragma unroll
    for (int o = 32; o >= 1; o >>= 1) mx = fmaxf(mx, __shfl_xor(mx, o));
    float sm = (lane < T) ? __expf(v - mx) : 0.f;
#pragma unroll
    for (int o = 32; o >= 1; o >>= 1) sm += __shfl_xor(sm, o);
    const float lp = mx + __logf(sm);
#pragma unroll
    for (int o = 32; o >= 1; o >>= 1) g += __shfl_xor(g, o);
    if (lane == 0) out[b] = lp - g;
  } else {
    // ================= viterbi: log domain, bit-exact =================
    float p = trS + e0;  // step-0 max collapses to prev=START (1e5 gap)
    if (lane < 32) bp[cur] = (unsigned char)START;

    float q0 = eb[1 * T], q1 = eb[2 * T], q2 = eb[3 * T], q3 = eb[4 * T];

#pragma unroll 4
    for (int s = 1; s < S; ++s) {
      float dpv[16];
#pragma unroll
      for (int i = 0; i < 16; ++i)
        dpv[i] = __int_as_float(
            __builtin_amdgcn_ds_bpermute(adr[i], __float_as_int(p)));
      float v[16];
#pragma unroll
      for (int i = 0; i < 16; ++i) v[i] = (tr[i] + q0) + dpv[i];  // ref order
      float mv[8]; int mi[8];
#pragma unroll
      for (int i = 0; i < 8; ++i) {
        const bool r = v[2 * i + 1] > v[2 * i];  // strict: ties -> lower idx
        mv[i] = r ? v[2 * i + 1] : v[2 * i];
        mi[i] = r ? 2 * i + 1 : 2 * i;
      }
#pragma unroll
      for (int i = 0; i < 4; ++i) {
        const bool r = mv[2 * i + 1] > mv[2 * i];
        mv[i] = r ? mv[2 * i + 1] : mv[2 * i];
        mi[i] = r ? mi[2 * i + 1] : mi[2 * i];
      }
#pragma unroll
      for (int i = 0; i < 2; ++i) {
        const bool r = mv[2 * i + 1] > mv[2 * i];
        mv[i] = r ? mv[2 * i + 1] : mv[2 * i];
        mi[i] = r ? mi[2 * i + 1] : mi[2 * i];
      }
      {
        const bool r = mv[1] > mv[0];
        mv[0] = r ? mv[1] : mv[0];
        mi[0] = r ? mi[1] : mi[0];
      }
      float best = mv[0];
      int arg = gbase + mi[0];
      // cross-half combine, first-index ties (round-2-proven shfl_xor)
      {
        const float ob = __shfl_xor(best, 32);
        const int oa = __shfl_xor(arg, 32);
        if (ob > best || (ob == best && oa < arg)) { best = ob; arg = oa; }
      }
      p = best;
      if (lane < 32) bp[s * T + cur] = (unsigned char)arg;
      const float nq = eb[((s + 4) & (S - 1)) * T];
      q0 = q1; q1 = q2; q2 = q3; q3 = nq;
    }

    // final argmax over tags (first-max tie-break)
    float v = (lane < T) ? p + trans[END * T + lane] : -3.0e38f;
    int a = lane;
#pragma unroll
    for (int o = 32; o >= 1; o >>= 1) {
      const float ov = __shfl_xor(v, o);
      const int oa = __shfl_xor(a, o);
      if (ov > v || (ov == v && oa < a)) { v = ov; a = oa; }
    }
    if (lane == 0) out[64 + 32768 + b] = v;
    __syncthreads();

    // ---- pointer-doubling backtrace ----
    // B1 = bp:  B1[s][t] = t_{s-1} given t_s = t.
    // B2[s] = B1[s-1] o B1[s]   (s>=1)  -> jA
    // B4[s] = B2[s-2] o B2[s]   (s>=3)  -> jB
    // B8[s] = B4[s-4] o B4[s]   (s>=7)  -> jA
    for (int idx = lane; idx < S * T; idx += 64) {
      const int s = idx >> 5;
      if (s >= 1) jA[idx] = bp[(s - 1) * T + bp[idx]];
    }
    __syncthreads();
    for (int idx = lane; idx < S * T; idx += 64) {
      const int s = idx >> 5;
      if (s >= 3) jB[idx] = jA[(s - 2) * T + jA[idx]];
    }
    __syncthreads();
    for (int idx = lane; idx < S * T; idx += 64) {
      const int s = idx >> 5;
      if (s >= 7) jA[idx] = jB[(s - 4) * T + jB[idx]];
    }
    __syncthreads();
    if (lane == 0) {
      int t = a;
      anch[0] = t;
      for (int j = 1; j < 64; ++j) {
        t = jA[(511 - 8 * (j - 1)) * T + t];  // jump 8: t_{s-8} = B8[s][t_s]
        anch[j] = t;
      }
    }
    __syncthreads();
    {
      int t = anch[lane];
      const int s0 = 511 - 8 * lane;
      pathb[s0] = (unsigned char)t;
#pragma unroll
      for (int k = 1; k < 8; ++k) {
        t = bp[(s0 - k + 1) * T + t];
        pathb[s0 - k] = (unsigned char)t;
      }
    }
    __syncthreads();
    for (int i = lane; i < S; i += 64) out[64 + b * S + i] = (float)pathb[i];
  }
}

// ---------------------------------------------------------------------------
extern "C" void kernel_launch(void* const* d_in, const int* in_sizes, int n_in,
                              void* d_out, int out_size, void* d_ws,
                              size_t ws_size, hipStream_t stream) {
  const float* emb = (const float*)d_in[0];
  const int* labels = (const int*)d_in[1];
  const float* W = (const float*)d_in[2];
  const float* bias = (const float*)d_in[3];
  const float* trans = (const float*)d_in[4];
  float* out = (float*)d_out;
  float* emitT = (float*)d_ws;  // 4 MiB scratch (ws_size verified in round 2)

  emit_gemm<<<S, 256, 0, stream>>>(emb, W, bias, emitT);
  crf_scan<<<2 * B, 64, 0, stream>>>(emitT, labels, trans, out);
}